// Round 2
// baseline (38.926 us; speedup 1.0000x reference)
//
#include <hip/hip_runtime.h>
#include <math.h>

#define BB 4
#define TT 2048
#define CE 32      // n_embd
#define NB 512     // T/4 blocks per sequence

// ---------------------------------------------------------------------------
// Kernel 1: Xavg[b][c][e] = mean over j of x[b][4j+c][e]   (b in 0..3, c in 0..3)
// ---------------------------------------------------------------------------
__global__ __launch_bounds__(256) void k_phase_avg(const float* __restrict__ x,
                                                   float* __restrict__ xavg) {
    int bc = blockIdx.x;            // b*4 + c
    int b = bc >> 2, c = bc & 3;
    int tid = threadIdx.x;
    int e  = tid & 31;
    int jg = tid >> 5;              // 0..7
    const float* xb = x + (size_t)b * TT * CE;
    float acc = 0.f;
    for (int j = jg; j < NB; j += 8)
        acc += xb[(size_t)(4 * j + c) * CE + e];
    __shared__ float red[8][32];
    red[jg][e] = acc;
    __syncthreads();
    if (tid < 32) {
        float s = 0.f;
#pragma unroll
        for (int g = 0; g < 8; ++g) s += red[g][tid];
        xavg[bc * 32 + tid] = s * (1.0f / (float)NB);
    }
}

__device__ __forceinline__ float clip100(float v) {
    return fminf(fmaxf(v, -100.f), 100.f);
}

// ---------------------------------------------------------------------------
// Kernel 2: one thread per token t. VERBATIM rxtx 26-mult formulas (they are
// NOT the clean Gram: c03 deviates by -2*X15*(-X1+X3+X5+X6-X7+X11)).
// grid = B * T/64 = 128 blocks, 64 threads.
// ---------------------------------------------------------------------------
__global__ __launch_bounds__(64) void k_attn(const float* __restrict__ x,
        const float* __restrict__ Wq, const float* __restrict__ bq,
        const float* __restrict__ Wv, const float* __restrict__ bv,
        const float* __restrict__ Wp, const float* __restrict__ bp,
        const float* __restrict__ xavg, float* __restrict__ out) {
    int blk = blockIdx.x;
    int b   = blk >> 5;                       // 32 blocks per batch
    int lt  = threadIdx.x;                    // 0..63
    int t   = ((blk & 31) << 6) + lt;

    __shared__ float qs[64][33];              // +1 pad kills stride-32 bank conflicts
    __shared__ float vavg[4][32];

    // Vavg[c][u] = bv[u] + sum_e Xavg[b][c][e] * Wv[u][e]
    {
        int u = lt & 31;
        const float* xa = xavg + b * 4 * 32;
        for (int c = (lt >> 5); c < 4; c += 2) {
            float acc = bv[u];
#pragma unroll
            for (int e = 0; e < 32; ++e)
                acc += xa[c * 32 + e] * Wv[u * 32 + e];
            vavg[c][u] = acc;
        }
    }

    // ---- x row -> registers ----
    float xr[32];
    const float* xrow = x + ((size_t)b * TT + t) * CE;
#pragma unroll
    for (int e = 0; e < 32; e += 4) {
        float4 v4 = *reinterpret_cast<const float4*>(xrow + e);
        xr[e] = v4.x; xr[e + 1] = v4.y; xr[e + 2] = v4.z; xr[e + 3] = v4.w;
    }

    // ---- q row ----
#pragma unroll 8
    for (int o = 0; o < 32; ++o) {
        float acc = bq[o];
#pragma unroll
        for (int e = 0; e < 32; ++e)
            acc += xr[e] * Wq[o * 32 + e];
        qs[lt][o] = acc;
    }
    __syncthreads();

    int r = lt & 3, ib = lt >> 2;
    float y[32];
#pragma unroll
    for (int h = 0; h < 8; ++h) {
        // X matrix of this thread's 4-token block, this head (clipped)
        float X1  = clip100(qs[ib * 4 + 0][h * 4 + 0]);
        float X2  = clip100(qs[ib * 4 + 0][h * 4 + 1]);
        float X3  = clip100(qs[ib * 4 + 0][h * 4 + 2]);
        float X4  = clip100(qs[ib * 4 + 0][h * 4 + 3]);
        float X5  = clip100(qs[ib * 4 + 1][h * 4 + 0]);
        float X6  = clip100(qs[ib * 4 + 1][h * 4 + 1]);
        float X7  = clip100(qs[ib * 4 + 1][h * 4 + 2]);
        float X8  = clip100(qs[ib * 4 + 1][h * 4 + 3]);
        float X9  = clip100(qs[ib * 4 + 2][h * 4 + 0]);
        float X10 = clip100(qs[ib * 4 + 2][h * 4 + 1]);
        float X11 = clip100(qs[ib * 4 + 2][h * 4 + 2]);
        float X12 = clip100(qs[ib * 4 + 2][h * 4 + 3]);
        float X13 = clip100(qs[ib * 4 + 3][h * 4 + 0]);
        float X14 = clip100(qs[ib * 4 + 3][h * 4 + 1]);
        float X15 = clip100(qs[ib * 4 + 3][h * 4 + 2]);
        float X16 = clip100(qs[ib * 4 + 3][h * 4 + 3]);

        // ---- verbatim 26-mult RXTX formulas ----
        float m1  = (-X2 + X3 - X4 + X8) * (X8 + X11);
        float m2  = (X1 - X5 - X6 + X7) * (X15 + X5);
        float m3  = (-X2 + X12) * (-X10 + X16 + X12);
        float m4  = (X9 - X6) * (X13 + X9 - X14);
        float m5  = (X2 + X11) * (-X6 + X15 - X7);
        float m6  = (X6 + X11) * (X6 + X7 - X11);
        float m7  = X11 * (X6 + X7);
        float m8  = X2 * (-X14 - X10 + X6 - X15 + X7 + X16 + X12);
        float m9  = X6 * (X13 + X9 - X14 - X10 + X6 + X7 - X11);
        float m10 = (X2 - X3 + X7 + X11 + X4 - X8) * X11;
        float m11 = (X5 + X6 - X7) * X5;
        float m12 = (X2 - X3 + X4) * X8;
        float m13 = (-X1 + X5 + X6 + X3 - X7 + X11) * X15;
        float m14 = (-X1 + X5 + X6) * (X13 + X9 + X15);
        float m15 = (X2 + X4 - X8) * (X11 + X16 + X12);
        float m16 = (X1 - X8) * (X9 - X16);
        float m17 = X12 * (X10 - X12);
        float m18 = X9 * (X13 - X14);
        float m19 = (-X2 + X3) * (-X15 + X7 + X8);
        float m20 = (X5 + X9 - X8) * X9;
        float m21 = X8 * (X9 - X8 + X12);
        float m22 = (-X6 + X7) * (X5 + X7 - X11);
        float m23 = X1 * (X13 - X5 + X16);
        float m24 = (-X1 + X4 + X12) * X16;
        float m25 = (X9 + X2 + X10) * X14;
        float m26 = (X6 + X10 + X12) * X10;
        float z1 = m7 - m11 - m12;
        float z2 = m1 + m12 + m21;
        float z3 = m3 + m17 - m24;
        float z4 = m2 + m11 + m23;
        float z5 = m5 + m7 + m8;
        float z6 = m4 - m18 - m20;
        float z7 = m6 - m7 - m9;
        float z8 = m17 + m18;
        float c01 = m2 - m5 - z1 + m13 + m19;
        float c02 = z2 + z3 + m15 + m16;
        float c03 = z4 - z3 - z5 - m13;
        float c11 = m1 + m6 - z1 + m10 + m22;
        float c12 = z2 - z6 + z7 + m10;
        float c13 = z4 + z6 + m14 + m16;
        float c22 = m4 - z7 - z8 + m26;
        float c23 = m3 + z5 + z8 + m25;

        float g0, g1, g2, g3;
        if (r == 0)      { g0 = 0.f; g1 = c01; g2 = c02; g3 = c03; }
        else if (r == 1) { g0 = c01; g1 = c11; g2 = c12; g3 = c13; }
        else if (r == 2) { g0 = c02; g1 = c12; g2 = c22; g3 = c23; }
        else             { g0 = c03; g1 = c13; g2 = c23; g3 = 0.f; }
        // clip C, clip scores (idempotent), /sqrt(4)
        g0 = clip100(g0) * 0.5f; g1 = clip100(g1) * 0.5f;
        g2 = clip100(g2) * 0.5f; g3 = clip100(g3) * 0.5f;

        float m  = fmaxf(fmaxf(g0, g1), fmaxf(g2, g3));
        float p0 = __expf(g0 - m), p1 = __expf(g1 - m);
        float p2 = __expf(g2 - m), p3 = __expf(g3 - m);
        float inv = 1.f / (p0 + p1 + p2 + p3);
        p0 *= inv; p1 *= inv; p2 *= inv; p3 *= inv;
#pragma unroll
        for (int d = 0; d < 4; ++d) {
            int u = h * 4 + d;
            y[u] = p0 * vavg[0][u] + p1 * vavg[1][u] +
                   p2 * vavg[2][u] + p3 * vavg[3][u];
        }
    }

    // ---- out row = y @ Wp.T + bp ----
    float* orow = out + ((size_t)b * TT + t) * CE;
#pragma unroll 2
    for (int o = 0; o < 32; o += 4) {
        float accs[4];
#pragma unroll
        for (int k = 0; k < 4; ++k) {
            float acc = bp[o + k];
#pragma unroll
            for (int u = 0; u < 32; ++u)
                acc += y[u] * Wp[(o + k) * 32 + u];
            accs[k] = acc;
        }
        float4 ov; ov.x = accs[0]; ov.y = accs[1]; ov.z = accs[2]; ov.w = accs[3];
        *reinterpret_cast<float4*>(orow + o) = ov;
    }
}

extern "C" void kernel_launch(void* const* d_in, const int* in_sizes, int n_in,
                              void* d_out, int out_size, void* d_ws, size_t ws_size,
                              hipStream_t stream) {
    const float* x  = (const float*)d_in[0];
    const float* Wq = (const float*)d_in[1];
    const float* bq = (const float*)d_in[2];
    // d_in[3] = Wk, d_in[4] = bk : computed in reference but unused
    const float* Wv = (const float*)d_in[5];
    const float* bv = (const float*)d_in[6];
    const float* Wp = (const float*)d_in[7];
    const float* bp = (const float*)d_in[8];
    float* out  = (float*)d_out;
    float* xavg = (float*)d_ws;   // 4*4*32 floats = 2 KiB

    hipLaunchKernelGGL(k_phase_avg, dim3(16), dim3(256), 0, stream, x, xavg);
    hipLaunchKernelGGL(k_attn, dim3(128), dim3(64), 0, stream,
                       x, Wq, bq, Wv, bv, Wp, bp, xavg, out);
}

// Round 3
// 18.164 us; speedup vs baseline: 2.1430x; 2.1430x over previous
//
#include <hip/hip_runtime.h>
#include <math.h>

#define TT 2048
#define CE 32

__device__ __forceinline__ float clip100(float v) {
    return fminf(fmaxf(v, -100.f), 100.f);
}

// ---------------------------------------------------------------------------
// Stage 1: x[b] viewed as [512][128]; xavg[b][c][e] = colmean[c*32+e].
// partial[b][cc][ch] = sum over rows 16*ch..16*ch+15 of col cc. (layout [4][128][32])
// grid = 128 blocks (b*32+ch), 256 threads. Coalesced 128B row loads.
// ---------------------------------------------------------------------------
__global__ __launch_bounds__(256) void k_avg1(const float* __restrict__ x,
                                              float* __restrict__ partial) {
    int blk = blockIdx.x;          // b*32 + ch
    int b = blk >> 5, ch = blk & 31;
    int tid = threadIdx.x;
    int cg = tid & 31;             // float4 col group (cols 4cg..4cg+3)
    int rp = tid >> 5;             // 0..7
    const float* base = x + ((size_t)b * 512 + (size_t)ch * 16) * 128;
    float4 a  = *reinterpret_cast<const float4*>(base + (size_t)rp * 128 + cg * 4);
    float4 b2 = *reinterpret_cast<const float4*>(base + (size_t)(rp + 8) * 128 + cg * 4);
    float4 s; s.x = a.x + b2.x; s.y = a.y + b2.y; s.z = a.z + b2.z; s.w = a.w + b2.w;
    __shared__ float4 red[8][32];
    red[rp][cg] = s;
    __syncthreads();
    if (rp == 0) {
        float4 acc = red[0][cg];
#pragma unroll
        for (int r2 = 1; r2 < 8; ++r2) {
            float4 v = red[r2][cg];
            acc.x += v.x; acc.y += v.y; acc.z += v.z; acc.w += v.w;
        }
        float* pb = partial + (size_t)b * 128 * 32;
        pb[(4 * cg + 0) * 32 + ch] = acc.x;
        pb[(4 * cg + 1) * 32 + ch] = acc.y;
        pb[(4 * cg + 2) * 32 + ch] = acc.z;
        pb[(4 * cg + 3) * 32 + ch] = acc.w;
    }
}

// ---------------------------------------------------------------------------
// Stage 2: one thread per (token, head). 256 blocks x 256 threads.
// Block handles 32 contiguous tokens of one batch (64 blocks/batch).
// Phases: [0: xavg finish | A: q GEMV -> qs] sync [B: rxtx->pbuf, Z build] sync
//         [C: out = bp + p @ Z]
// ---------------------------------------------------------------------------
__global__ __launch_bounds__(256) void k_attn(const float* __restrict__ x,
        const float* __restrict__ Wq, const float* __restrict__ bq,
        const float* __restrict__ Wv, const float* __restrict__ bv,
        const float* __restrict__ Wp, const float* __restrict__ bp,
        const float* __restrict__ partial, float* __restrict__ out) {
    int blk = blockIdx.x;
    int b   = blk >> 6;                    // 64 blocks per batch
    int t0  = (blk & 63) * 32;             // first token (within batch)
    int tid = threadIdx.x;
    int tl  = tid >> 3;                    // token local 0..31
    int h   = tid & 7;                     // head 0..7

    __shared__ float qs[32][40];           // clipped q rows; stride 40 (2-way max)
    __shared__ float pbuf[32][36];         // softmax p, k=(h*4+c)
    __shared__ float Zl[32][36];           // Z[k][o]
    __shared__ float xavg[4][33];          // phase means

    // ---- phase 0: finish column mean (threads 0..127) ----
    if (tid < 128) {
        int cc = tid;
        const float* pp = partial + (size_t)b * 128 * 32 + (size_t)cc * 32;
        float s = 0.f;
#pragma unroll
        for (int c4 = 0; c4 < 8; ++c4) {
            float4 v = *reinterpret_cast<const float4*>(pp + c4 * 4);
            s += v.x + v.y + v.z + v.w;
        }
        xavg[cc >> 5][cc & 31] = s * (1.f / 512.f);
    }

    // ---- phase A: q[t][4h+d], d=0..3 ----
    {
        const float* xrow = x + ((size_t)b * TT + t0 + tl) * CE;
        float acc0 = bq[4 * h + 0], acc1 = bq[4 * h + 1];
        float acc2 = bq[4 * h + 2], acc3 = bq[4 * h + 3];
#pragma unroll
        for (int e4 = 0; e4 < 8; ++e4) {
            float4 xv = *reinterpret_cast<const float4*>(xrow + e4 * 4);
            float4 w0 = *reinterpret_cast<const float4*>(Wq + (4 * h + 0) * 32 + e4 * 4);
            float4 w1 = *reinterpret_cast<const float4*>(Wq + (4 * h + 1) * 32 + e4 * 4);
            float4 w2 = *reinterpret_cast<const float4*>(Wq + (4 * h + 2) * 32 + e4 * 4);
            float4 w3 = *reinterpret_cast<const float4*>(Wq + (4 * h + 3) * 32 + e4 * 4);
            acc0 += xv.x * w0.x + xv.y * w0.y + xv.z * w0.z + xv.w * w0.w;
            acc1 += xv.x * w1.x + xv.y * w1.y + xv.z * w1.z + xv.w * w1.w;
            acc2 += xv.x * w2.x + xv.y * w2.y + xv.z * w2.z + xv.w * w2.w;
            acc3 += xv.x * w3.x + xv.y * w3.y + xv.z * w3.z + xv.w * w3.w;
        }
        float4 qv;
        qv.x = clip100(acc0); qv.y = clip100(acc1);
        qv.z = clip100(acc2); qv.w = clip100(acc3);
        *reinterpret_cast<float4*>(&qs[tl][4 * h]) = qv;
    }
    __syncthreads();

    // ---- phase B1: rxtx + softmax for (token tl, head h) ----
    {
        int b4 = tl >> 2, r = tl & 3;
        float4 R0 = *reinterpret_cast<const float4*>(&qs[4 * b4 + 0][4 * h]);
        float4 R1 = *reinterpret_cast<const float4*>(&qs[4 * b4 + 1][4 * h]);
        float4 R2 = *reinterpret_cast<const float4*>(&qs[4 * b4 + 2][4 * h]);
        float4 R3 = *reinterpret_cast<const float4*>(&qs[4 * b4 + 3][4 * h]);
        float X1 = R0.x, X2 = R0.y, X3 = R0.z, X4 = R0.w;
        float X5 = R1.x, X6 = R1.y, X7 = R1.z, X8 = R1.w;
        float X9 = R2.x, X10 = R2.y, X11 = R2.z, X12 = R2.w;
        float X13 = R3.x, X14 = R3.y, X15 = R3.z, X16 = R3.w;

        float m1  = (-X2 + X3 - X4 + X8) * (X8 + X11);
        float m2  = (X1 - X5 - X6 + X7) * (X15 + X5);
        float m3  = (-X2 + X12) * (-X10 + X16 + X12);
        float m4  = (X9 - X6) * (X13 + X9 - X14);
        float m5  = (X2 + X11) * (-X6 + X15 - X7);
        float m6  = (X6 + X11) * (X6 + X7 - X11);
        float m7  = X11 * (X6 + X7);
        float m8  = X2 * (-X14 - X10 + X6 - X15 + X7 + X16 + X12);
        float m9  = X6 * (X13 + X9 - X14 - X10 + X6 + X7 - X11);
        float m10 = (X2 - X3 + X7 + X11 + X4 - X8) * X11;
        float m11 = (X5 + X6 - X7) * X5;
        float m12 = (X2 - X3 + X4) * X8;
        float m13 = (-X1 + X5 + X6 + X3 - X7 + X11) * X15;
        float m14 = (-X1 + X5 + X6) * (X13 + X9 + X15);
        float m15 = (X2 + X4 - X8) * (X11 + X16 + X12);
        float m16 = (X1 - X8) * (X9 - X16);
        float m17 = X12 * (X10 - X12);
        float m18 = X9 * (X13 - X14);
        float m19 = (-X2 + X3) * (-X15 + X7 + X8);
        float m20 = (X5 + X9 - X8) * X9;
        float m21 = X8 * (X9 - X8 + X12);
        float m22 = (-X6 + X7) * (X5 + X7 - X11);
        float m23 = X1 * (X13 - X5 + X16);
        float m24 = (-X1 + X4 + X12) * X16;
        float m25 = (X9 + X2 + X10) * X14;
        float m26 = (X6 + X10 + X12) * X10;
        float z1 = m7 - m11 - m12;
        float z2 = m1 + m12 + m21;
        float z3 = m3 + m17 - m24;
        float z4 = m2 + m11 + m23;
        float z5 = m5 + m7 + m8;
        float z6 = m4 - m18 - m20;
        float z7 = m6 - m7 - m9;
        float z8 = m17 + m18;
        float c01 = m2 - m5 - z1 + m13 + m19;
        float c02 = z2 + z3 + m15 + m16;
        float c03 = z4 - z3 - z5 - m13;
        float c11 = m1 + m6 - z1 + m10 + m22;
        float c12 = z2 - z6 + z7 + m10;
        float c13 = z4 + z6 + m14 + m16;
        float c22 = m4 - z7 - z8 + m26;
        float c23 = m3 + z5 + z8 + m25;

        float g0, g1, g2, g3;
        if (r == 0)      { g0 = 0.f; g1 = c01; g2 = c02; g3 = c03; }
        else if (r == 1) { g0 = c01; g1 = c11; g2 = c12; g3 = c13; }
        else if (r == 2) { g0 = c02; g1 = c12; g2 = c22; g3 = c23; }
        else             { g0 = c03; g1 = c13; g2 = c23; g3 = 0.f; }
        g0 = clip100(g0) * 0.5f; g1 = clip100(g1) * 0.5f;
        g2 = clip100(g2) * 0.5f; g3 = clip100(g3) * 0.5f;

        float mx = fmaxf(fmaxf(g0, g1), fmaxf(g2, g3));
        float p0 = __expf(g0 - mx), p1 = __expf(g1 - mx);
        float p2 = __expf(g2 - mx), p3 = __expf(g3 - mx);
        float inv = 1.f / (p0 + p1 + p2 + p3);
        float4 pv; pv.x = p0 * inv; pv.y = p1 * inv; pv.z = p2 * inv; pv.w = p3 * inv;
        *reinterpret_cast<float4*>(&pbuf[tl][4 * h]) = pv;
    }

    // ---- phase B2: Z[k][o] for k = tid>>3, o = 4*(tid&7)..+3 ----
    {
        int k  = tid >> 3;       // 0..31 : k = h2*4 + c2
        int oq = tid & 7;
        int h2 = k >> 2, c2 = k & 3;
        float vv0 = bv[4 * h2 + 0], vv1 = bv[4 * h2 + 1];
        float vv2 = bv[4 * h2 + 2], vv3 = bv[4 * h2 + 3];
#pragma unroll
        for (int e4 = 0; e4 < 8; ++e4) {
            float xa0 = xavg[c2][e4 * 4 + 0];
            float xa1 = xavg[c2][e4 * 4 + 1];
            float xa2 = xavg[c2][e4 * 4 + 2];
            float xa3 = xavg[c2][e4 * 4 + 3];
            float4 w0 = *reinterpret_cast<const float4*>(Wv + (4 * h2 + 0) * 32 + e4 * 4);
            float4 w1 = *reinterpret_cast<const float4*>(Wv + (4 * h2 + 1) * 32 + e4 * 4);
            float4 w2 = *reinterpret_cast<const float4*>(Wv + (4 * h2 + 2) * 32 + e4 * 4);
            float4 w3 = *reinterpret_cast<const float4*>(Wv + (4 * h2 + 3) * 32 + e4 * 4);
            vv0 += xa0 * w0.x + xa1 * w0.y + xa2 * w0.z + xa3 * w0.w;
            vv1 += xa0 * w1.x + xa1 * w1.y + xa2 * w1.z + xa3 * w1.w;
            vv2 += xa0 * w2.x + xa1 * w2.y + xa2 * w2.z + xa3 * w2.w;
            vv3 += xa0 * w3.x + xa1 * w3.y + xa2 * w3.z + xa3 * w3.w;
        }
        float4 zv;
        float* zp = &Zl[k][4 * oq];
#pragma unroll
        for (int dd = 0; dd < 4; ++dd) {
            float4 wp = *reinterpret_cast<const float4*>(Wp + (size_t)(4 * oq + dd) * 32 + 4 * h2);
            float z = vv0 * wp.x + vv1 * wp.y + vv2 * wp.z + vv3 * wp.w;
            ((float*)&zv)[dd] = z;
        }
        *reinterpret_cast<float4*>(zp) = zv;
    }
    __syncthreads();

    // ---- phase C: out[t][4j+d] = bp + sum_k p[k] * Z[k][4j+d] ----
    {
        int j = h;
        float o0 = bp[4 * j + 0], o1 = bp[4 * j + 1];
        float o2 = bp[4 * j + 2], o3 = bp[4 * j + 3];
#pragma unroll
        for (int k4 = 0; k4 < 8; ++k4) {
            float4 pv = *reinterpret_cast<const float4*>(&pbuf[tl][4 * k4]);
#pragma unroll
            for (int kk = 0; kk < 4; ++kk) {
                float p = ((const float*)&pv)[kk];
                float4 zv = *reinterpret_cast<const float4*>(&Zl[4 * k4 + kk][4 * j]);
                o0 += p * zv.x; o1 += p * zv.y; o2 += p * zv.z; o3 += p * zv.w;
            }
        }
        float4 ov; ov.x = o0; ov.y = o1; ov.z = o2; ov.w = o3;
        float* orow = out + ((size_t)b * TT + t0 + tl) * CE;
        *reinterpret_cast<float4*>(orow + 4 * j) = ov;
    }
}

extern "C" void kernel_launch(void* const* d_in, const int* in_sizes, int n_in,
                              void* d_out, int out_size, void* d_ws, size_t ws_size,
                              hipStream_t stream) {
    const float* x  = (const float*)d_in[0];
    const float* Wq = (const float*)d_in[1];
    const float* bq = (const float*)d_in[2];
    // d_in[3] = Wk, d_in[4] = bk : unused by the reference math
    const float* Wv = (const float*)d_in[5];
    const float* bv = (const float*)d_in[6];
    const float* Wp = (const float*)d_in[7];
    const float* bp = (const float*)d_in[8];
    float* out     = (float*)d_out;
    float* partial = (float*)d_ws;   // 4*128*32 floats = 64 KiB

    hipLaunchKernelGGL(k_avg1, dim3(128), dim3(256), 0, stream, x, partial);
    hipLaunchKernelGGL(k_attn, dim3(256), dim3(256), 0, stream,
                       x, Wq, bq, Wv, bv, Wp, bp, partial, out);
}

// Round 4
// 16.608 us; speedup vs baseline: 2.3438x; 1.0937x over previous
//
#include <hip/hip_runtime.h>
#include <math.h>

#define TT 2048
#define CE 32

__device__ __forceinline__ float clip100(float v) {
    return fminf(fmaxf(v, -100.f), 100.f);
}

__device__ __forceinline__ float4 shfl_xor4(float4 v, int m) {
    float4 r;
    r.x = __shfl_xor(v.x, m, 64);
    r.y = __shfl_xor(v.y, m, 64);
    r.z = __shfl_xor(v.z, m, 64);
    r.w = __shfl_xor(v.w, m, 64);
    return r;
}

// ---------------------------------------------------------------------------
// Stage 1: x[b] viewed as [512][128]; partial[b][cc][ch] = sum of rows
// 16ch..16ch+15 of col cc.  grid = 128 blocks (b*32+ch), 256 threads.
// ---------------------------------------------------------------------------
__global__ __launch_bounds__(256) void k_avg1(const float* __restrict__ x,
                                              float* __restrict__ partial) {
    int blk = blockIdx.x;          // b*32 + ch
    int b = blk >> 5, ch = blk & 31;
    int tid = threadIdx.x;
    int cg = tid & 31;             // float4 col group
    int rp = tid >> 5;             // 0..7
    const float* base = x + ((size_t)b * 512 + (size_t)ch * 16) * 128;
    float4 a  = *reinterpret_cast<const float4*>(base + (size_t)rp * 128 + cg * 4);
    float4 b2 = *reinterpret_cast<const float4*>(base + (size_t)(rp + 8) * 128 + cg * 4);
    float4 s; s.x = a.x + b2.x; s.y = a.y + b2.y; s.z = a.z + b2.z; s.w = a.w + b2.w;
    __shared__ float4 red[8][32];
    red[rp][cg] = s;
    __syncthreads();
    if (rp == 0) {
        float4 acc = red[0][cg];
#pragma unroll
        for (int r2 = 1; r2 < 8; ++r2) {
            float4 v = red[r2][cg];
            acc.x += v.x; acc.y += v.y; acc.z += v.z; acc.w += v.w;
        }
        float* pb = partial + (size_t)b * 128 * 32;
        pb[(4 * cg + 0) * 32 + ch] = acc.x;
        pb[(4 * cg + 1) * 32 + ch] = acc.y;
        pb[(4 * cg + 2) * 32 + ch] = acc.z;
        pb[(4 * cg + 3) * 32 + ch] = acc.w;
    }
}

// ---------------------------------------------------------------------------
// Stage 2: 512 blocks x 256 threads; block = 16 tokens of one batch.
// thread tid = tl*16 + h*2 + s  (tl 0..15 token, h 0..7 head, s e/k-half).
// Wave holds 4 tokens (one rxtx block) -> q exchange fully in-wave via shfl.
// Phases: [stage LDS: x-tile, Wq/Wv/Wp/biases, xavg-finish] sync
//         [A: q half-dots + shfl combine + rxtx + softmax -> pbuf; B2: Z -> Zl]
//         sync [C: out = bp + p@Z, split-k + shfl combine]
// ---------------------------------------------------------------------------
__global__ __launch_bounds__(256) void k_attn(const float* __restrict__ x,
        const float* __restrict__ Wq, const float* __restrict__ bq,
        const float* __restrict__ Wv, const float* __restrict__ bv,
        const float* __restrict__ Wp, const float* __restrict__ bp,
        const float* __restrict__ partial, float* __restrict__ out) {
    int blk = blockIdx.x;
    int b   = blk >> 7;                    // 128 blocks per batch
    int t0  = (blk & 127) * 16;
    int tid = threadIdx.x;
    int tl  = tid >> 4;                    // 0..15
    int h   = (tid >> 1) & 7;              // 0..7
    int s   = tid & 1;                     // 0..1

    __shared__ float xs[16][33];
    __shared__ float wqs[32][33];
    __shared__ float wvs[32][33];
    __shared__ float wps[32][33];
    __shared__ float pbuf[16][36];
    __shared__ float Zl[32][36];
    __shared__ float xavg[4][33];
    __shared__ float bqs[32], bvs[32], bps[32];

    // ---- stage: weights (1 quad each), x tile, biases, xavg finish ----
    {
        int rr = tid >> 3, cq = tid & 7;
        *reinterpret_cast<float4*>(&wqs[rr][cq * 4]) =
            *reinterpret_cast<const float4*>(Wq + rr * 32 + cq * 4);
        *reinterpret_cast<float4*>(&wvs[rr][cq * 4]) =
            *reinterpret_cast<const float4*>(Wv + rr * 32 + cq * 4);
        *reinterpret_cast<float4*>(&wps[rr][cq * 4]) =
            *reinterpret_cast<const float4*>(Wp + rr * 32 + cq * 4);
        if (tid < 128) {
            int r2 = tid >> 3, q2 = tid & 7;
            *reinterpret_cast<float4*>(&xs[r2][q2 * 4]) =
                *reinterpret_cast<const float4*>(x + ((size_t)b * TT + t0 + r2) * CE + q2 * 4);
        } else {
            int u = tid - 128;
            if (u < 32)      bqs[u] = bq[u];
            else if (u < 64) bvs[u - 32] = bv[u - 32];
            else if (u < 96) bps[u - 64] = bp[u - 64];
        }
        if (tid < 128) {
            int cc = tid;
            const float* pp = partial + (size_t)b * 128 * 32 + (size_t)cc * 32;
            float sm = 0.f;
#pragma unroll
            for (int c4 = 0; c4 < 8; ++c4) {
                float4 v = *reinterpret_cast<const float4*>(pp + c4 * 4);
                sm += v.x + v.y + v.z + v.w;
            }
            xavg[cc >> 5][cc & 31] = sm * (1.f / 512.f);
        }
    }
    __syncthreads();

    // ---- phase A: q half-dot (e-range s*16..s*16+15), combine via shfl ----
    float4 myq;
    {
        float a0 = 0.f, a1 = 0.f, a2 = 0.f, a3 = 0.f;
#pragma unroll
        for (int e4 = 0; e4 < 4; ++e4) {
            int e = s * 16 + e4 * 4;
            float4 xv = *reinterpret_cast<const float4*>(&xs[tl][e]);
            float4 w0 = *reinterpret_cast<const float4*>(&wqs[4 * h + 0][e]);
            float4 w1 = *reinterpret_cast<const float4*>(&wqs[4 * h + 1][e]);
            float4 w2 = *reinterpret_cast<const float4*>(&wqs[4 * h + 2][e]);
            float4 w3 = *reinterpret_cast<const float4*>(&wqs[4 * h + 3][e]);
            a0 += xv.x * w0.x + xv.y * w0.y + xv.z * w0.z + xv.w * w0.w;
            a1 += xv.x * w1.x + xv.y * w1.y + xv.z * w1.z + xv.w * w1.w;
            a2 += xv.x * w2.x + xv.y * w2.y + xv.z * w2.z + xv.w * w2.w;
            a3 += xv.x * w3.x + xv.y * w3.y + xv.z * w3.z + xv.w * w3.w;
        }
        myq.x = clip100(bqs[4 * h + 0] + a0 + __shfl_xor(a0, 1, 64));
        myq.y = clip100(bqs[4 * h + 1] + a1 + __shfl_xor(a1, 1, 64));
        myq.z = clip100(bqs[4 * h + 2] + a2 + __shfl_xor(a2, 1, 64));
        myq.w = clip100(bqs[4 * h + 3] + a3 + __shfl_xor(a3, 1, 64));
    }

    // ---- q-block exchange fully in-wave: tl bits 0,1 live at tid bits 4,5 ----
    {
        int r = tl & 3;
        float4 q16 = shfl_xor4(myq, 16);   // row r^1
        float4 q32 = shfl_xor4(myq, 32);   // row r^2
        float4 q48 = shfl_xor4(myq, 48);   // row r^3
        float4 R0 = (r == 0) ? myq : (r == 1) ? q16 : (r == 2) ? q32 : q48;
        float4 R1 = (r == 1) ? myq : (r == 0) ? q16 : (r == 3) ? q32 : q48;
        float4 R2 = (r == 2) ? myq : (r == 3) ? q16 : (r == 0) ? q32 : q48;
        float4 R3 = (r == 3) ? myq : (r == 2) ? q16 : (r == 1) ? q32 : q48;

        float X1 = R0.x, X2 = R0.y, X3 = R0.z, X4 = R0.w;
        float X5 = R1.x, X6 = R1.y, X7 = R1.z, X8 = R1.w;
        float X9 = R2.x, X10 = R2.y, X11 = R2.z, X12 = R2.w;
        float X13 = R3.x, X14 = R3.y, X15 = R3.z, X16 = R3.w;

        float m1  = (-X2 + X3 - X4 + X8) * (X8 + X11);
        float m2  = (X1 - X5 - X6 + X7) * (X15 + X5);
        float m3  = (-X2 + X12) * (-X10 + X16 + X12);
        float m4  = (X9 - X6) * (X13 + X9 - X14);
        float m5  = (X2 + X11) * (-X6 + X15 - X7);
        float m6  = (X6 + X11) * (X6 + X7 - X11);
        float m7  = X11 * (X6 + X7);
        float m8  = X2 * (-X14 - X10 + X6 - X15 + X7 + X16 + X12);
        float m9  = X6 * (X13 + X9 - X14 - X10 + X6 + X7 - X11);
        float m10 = (X2 - X3 + X7 + X11 + X4 - X8) * X11;
        float m11 = (X5 + X6 - X7) * X5;
        float m12 = (X2 - X3 + X4) * X8;
        float m13 = (-X1 + X5 + X6 + X3 - X7 + X11) * X15;
        float m14 = (-X1 + X5 + X6) * (X13 + X9 + X15);
        float m15 = (X2 + X4 - X8) * (X11 + X16 + X12);
        float m16 = (X1 - X8) * (X9 - X16);
        float m17 = X12 * (X10 - X12);
        float m18 = X9 * (X13 - X14);
        float m19 = (-X2 + X3) * (-X15 + X7 + X8);
        float m20 = (X5 + X9 - X8) * X9;
        float m21 = X8 * (X9 - X8 + X12);
        float m22 = (-X6 + X7) * (X5 + X7 - X11);
        float m23 = X1 * (X13 - X5 + X16);
        float m24 = (-X1 + X4 + X12) * X16;
        float m25 = (X9 + X2 + X10) * X14;
        float m26 = (X6 + X10 + X12) * X10;
        float z1 = m7 - m11 - m12;
        float z2 = m1 + m12 + m21;
        float z3 = m3 + m17 - m24;
        float z4 = m2 + m11 + m23;
        float z5 = m5 + m7 + m8;
        float z6 = m4 - m18 - m20;
        float z7 = m6 - m7 - m9;
        float z8 = m17 + m18;
        float c01 = m2 - m5 - z1 + m13 + m19;
        float c02 = z2 + z3 + m15 + m16;
        float c03 = z4 - z3 - z5 - m13;
        float c11 = m1 + m6 - z1 + m10 + m22;
        float c12 = z2 - z6 + z7 + m10;
        float c13 = z4 + z6 + m14 + m16;
        float c22 = m4 - z7 - z8 + m26;
        float c23 = m3 + z5 + z8 + m25;

        float g0, g1, g2, g3;
        if (r == 0)      { g0 = 0.f; g1 = c01; g2 = c02; g3 = c03; }
        else if (r == 1) { g0 = c01; g1 = c11; g2 = c12; g3 = c13; }
        else if (r == 2) { g0 = c02; g1 = c12; g2 = c22; g3 = c23; }
        else             { g0 = c03; g1 = c13; g2 = c23; g3 = 0.f; }
        g0 = clip100(g0) * 0.5f; g1 = clip100(g1) * 0.5f;
        g2 = clip100(g2) * 0.5f; g3 = clip100(g3) * 0.5f;

        float mx = fmaxf(fmaxf(g0, g1), fmaxf(g2, g3));
        float p0 = __expf(g0 - mx), p1 = __expf(g1 - mx);
        float p2 = __expf(g2 - mx), p3 = __expf(g3 - mx);
        float inv = 1.f / (p0 + p1 + p2 + p3);
        if (s == 0) {
            float4 pv; pv.x = p0 * inv; pv.y = p1 * inv;
            pv.z = p2 * inv; pv.w = p3 * inv;
            *reinterpret_cast<float4*>(&pbuf[tl][4 * h]) = pv;
        }
    }

    // ---- phase B2: Z[k][4oq..] for task tid (k = tid>>3, oq = tid&7) ----
    {
        int k  = tid >> 3;       // 0..31
        int oq = tid & 7;
        int h2 = k >> 2, c2 = k & 3;
        float vv0 = bvs[4 * h2 + 0], vv1 = bvs[4 * h2 + 1];
        float vv2 = bvs[4 * h2 + 2], vv3 = bvs[4 * h2 + 3];
#pragma unroll
        for (int e4 = 0; e4 < 8; ++e4) {
            float xa0 = xavg[c2][e4 * 4 + 0];
            float xa1 = xavg[c2][e4 * 4 + 1];
            float xa2 = xavg[c2][e4 * 4 + 2];
            float xa3 = xavg[c2][e4 * 4 + 3];
            float4 w0 = *reinterpret_cast<const float4*>(&wvs[4 * h2 + 0][e4 * 4]);
            float4 w1 = *reinterpret_cast<const float4*>(&wvs[4 * h2 + 1][e4 * 4]);
            float4 w2 = *reinterpret_cast<const float4*>(&wvs[4 * h2 + 2][e4 * 4]);
            float4 w3 = *reinterpret_cast<const float4*>(&wvs[4 * h2 + 3][e4 * 4]);
            vv0 += xa0 * w0.x + xa1 * w0.y + xa2 * w0.z + xa3 * w0.w;
            vv1 += xa0 * w1.x + xa1 * w1.y + xa2 * w1.z + xa3 * w1.w;
            vv2 += xa0 * w2.x + xa1 * w2.y + xa2 * w2.z + xa3 * w2.w;
            vv3 += xa0 * w3.x + xa1 * w3.y + xa2 * w3.z + xa3 * w3.w;
        }
        float4 zv;
#pragma unroll
        for (int dd = 0; dd < 4; ++dd) {
            float4 wp = *reinterpret_cast<const float4*>(&wps[4 * oq + dd][4 * h2]);
            ((float*)&zv)[dd] = vv0 * wp.x + vv1 * wp.y + vv2 * wp.z + vv3 * wp.w;
        }
        *reinterpret_cast<float4*>(&Zl[k][4 * oq]) = zv;
    }
    __syncthreads();

    // ---- phase C: out[t][4j+d], split over k-halves (16 k's each) ----
    {
        int j = h;
        float o0 = 0.f, o1 = 0.f, o2 = 0.f, o3 = 0.f;
#pragma unroll
        for (int k4 = 0; k4 < 4; ++k4) {
            float4 pv = *reinterpret_cast<const float4*>(&pbuf[tl][16 * s + 4 * k4]);
#pragma unroll
            for (int kk = 0; kk < 4; ++kk) {
                float p = ((const float*)&pv)[kk];
                float4 zv = *reinterpret_cast<const float4*>(&Zl[16 * s + 4 * k4 + kk][4 * j]);
                o0 += p * zv.x; o1 += p * zv.y; o2 += p * zv.z; o3 += p * zv.w;
            }
        }
        o0 += __shfl_xor(o0, 1, 64); o1 += __shfl_xor(o1, 1, 64);
        o2 += __shfl_xor(o2, 1, 64); o3 += __shfl_xor(o3, 1, 64);
        if (s == 0) {
            float4 ov;
            ov.x = bps[4 * j + 0] + o0; ov.y = bps[4 * j + 1] + o1;
            ov.z = bps[4 * j + 2] + o2; ov.w = bps[4 * j + 3] + o3;
            float* orow = out + ((size_t)b * TT + t0 + tl) * CE;
            *reinterpret_cast<float4*>(orow + 4 * j) = ov;
        }
    }
}

extern "C" void kernel_launch(void* const* d_in, const int* in_sizes, int n_in,
                              void* d_out, int out_size, void* d_ws, size_t ws_size,
                              hipStream_t stream) {
    const float* x  = (const float*)d_in[0];
    const float* Wq = (const float*)d_in[1];
    const float* bq = (const float*)d_in[2];
    // d_in[3] = Wk, d_in[4] = bk : unused by the reference math
    const float* Wv = (const float*)d_in[5];
    const float* bv = (const float*)d_in[6];
    const float* Wp = (const float*)d_in[7];
    const float* bp = (const float*)d_in[8];
    float* out     = (float*)d_out;
    float* partial = (float*)d_ws;   // 4*128*32 floats = 64 KiB

    hipLaunchKernelGGL(k_avg1, dim3(128), dim3(256), 0, stream, x, partial);
    hipLaunchKernelGGL(k_attn, dim3(512), dim3(256), 0, stream,
                       x, Wq, bq, Wv, bv, Wp, bp, partial, out);
}